// Round 1
// baseline (1243.125 us; speedup 1.0000x reference)
//
#include <hip/hip_runtime.h>
#include <math.h>

#define T_LEN 2048
#define HIDN  2048
#define HKN   16
#define DKN   96
#define HVN   16
#define DVN   192
#define KDIMN 1536
#define VDIMN 3072
#define NPROJ 9216   // 1536+1536+3072+3072 (q,k,v,gate)
#define CHUNKN 64
#define NCHUNK 32
#define EPSF 1e-6f

typedef __attribute__((ext_vector_type(8))) short short8;
typedef __attribute__((ext_vector_type(4))) float f32x4;

__device__ __forceinline__ unsigned short f2bf(float f) {
    unsigned int u = __float_as_uint(f);
    unsigned int r = (u + 0x7FFFu + ((u >> 16) & 1u)) >> 16;
    return (unsigned short)r;
}
__device__ __forceinline__ float siluf(float x) { return x / (1.f + expf(-x)); }

// ---------------- cast f32 -> bf16 (4/thread) ----------------
__global__ void cast_f32_bf16(const float* __restrict__ in, unsigned short* __restrict__ out, int n) {
    int i = (blockIdx.x * blockDim.x + threadIdx.x) * 4;
    if (i >= n) return;
    float4 v = *(const float4*)(in + i);
    ushort4 o;
    o.x = f2bf(v.x); o.y = f2bf(v.y); o.z = f2bf(v.z); o.w = f2bf(v.w);
    *(ushort4*)(out + i) = o;
}

// ---------------- transpose + cast: W[K][N] -> Wt[N][K] bf16 ----------------
__global__ void transpose_cast(const float* __restrict__ W, unsigned short* __restrict__ Wt,
                               int K, int N) {
    __shared__ float tile[64][65];
    int k0 = blockIdx.y * 64, n0 = blockIdx.x * 64;
    int tx = threadIdx.x, ty = threadIdx.y; // (64,4)
    for (int r = ty; r < 64; r += 4) tile[r][tx] = W[(size_t)(k0 + r) * N + n0 + tx];
    __syncthreads();
    for (int r = ty; r < 64; r += 4) Wt[(size_t)(n0 + r) * K + k0 + tx] = f2bf(tile[tx][r]);
}

// ---------------- bf16 MFMA GEMM: C[M][N] f32 = A[M][K] @ Bt[N][K]^T ----------------
// 128x128 tile, 4 waves (2x2), each wave 64x64 via 4x4 frags of 16x16x32, BK=32.
__global__ __launch_bounds__(256) void gemm_bt(const unsigned short* __restrict__ A,
                                               const unsigned short* __restrict__ Bt,
                                               float* __restrict__ C, int M, int N, int K) {
    __shared__ __align__(16) unsigned short As[128 * 32];
    __shared__ __align__(16) unsigned short Bs[128 * 32];
    int tid = threadIdx.x;
    int wave = tid >> 6, lane = tid & 63;
    int bm = blockIdx.y, bn = blockIdx.x;
    f32x4 acc[4][4] = {};
    int wr = wave >> 1, wc = wave & 1;
    int rstage = wave * 32 + (lane >> 2);      // tile row for staging
    int cstage = (lane & 3) * 8;               // k-offset within BK (elements)
    const size_t a_row0 = (size_t)bm * 128;
    const size_t b_row0 = (size_t)bn * 128;
    int row_a[4], row_b[4];
#pragma unroll
    for (int i = 0; i < 4; ++i) {
        row_a[i] = wr * 64 + i * 16 + (lane & 15);
        row_b[i] = wc * 64 + i * 16 + (lane & 15);
    }
    int koff = (lane >> 4) * 8;
    for (int k0 = 0; k0 < K; k0 += 32) {
#pragma unroll
        for (int e = 0; e < 2; ++e) {
            int r = rstage + e * 16;
            short8 va = *(const short8*)(A + (a_row0 + r) * K + k0 + cstage);
            short8 vb = *(const short8*)(Bt + (b_row0 + r) * K + k0 + cstage);
            *(short8*)(As + r * 32 + cstage) = va;
            *(short8*)(Bs + r * 32 + cstage) = vb;
        }
        __syncthreads();
        short8 af[4], bfr[4];
#pragma unroll
        for (int mi = 0; mi < 4; ++mi) af[mi] = *(const short8*)(As + row_a[mi] * 32 + koff);
#pragma unroll
        for (int ni = 0; ni < 4; ++ni) bfr[ni] = *(const short8*)(Bs + row_b[ni] * 32 + koff);
#pragma unroll
        for (int mi = 0; mi < 4; ++mi)
#pragma unroll
            for (int ni = 0; ni < 4; ++ni)
                acc[mi][ni] = __builtin_amdgcn_mfma_f32_16x16x32_bf16(af[mi], bfr[ni], acc[mi][ni], 0, 0, 0);
        __syncthreads();
    }
#pragma unroll
    for (int mi = 0; mi < 4; ++mi) {
        int rbase = bm * 128 + wr * 64 + mi * 16 + (lane >> 4) * 4;
#pragma unroll
        for (int ni = 0; ni < 4; ++ni) {
            int col = bn * 128 + wc * 64 + ni * 16 + (lane & 15);
#pragma unroll
            for (int j = 0; j < 4; ++j)
                C[(size_t)(rbase + j) * N + col] = acc[mi][ni][j];
        }
    }
}

// ---------------- causal depthwise conv(K=4) + SiLU ----------------
__global__ void conv_silu(const float* __restrict__ pre, int ldp,
                          const float* __restrict__ wconv, float* __restrict__ out, int C) {
    int c = blockIdx.x * blockDim.x + threadIdx.x;
    int t = blockIdx.y;
    if (c >= C) return;
    const float* wc4 = wconv + (size_t)c * 4;
    float acc = 0.f;
    if (t >= 3) acc += pre[(size_t)(t - 3) * ldp + c] * wc4[0];
    if (t >= 2) acc += pre[(size_t)(t - 2) * ldp + c] * wc4[1];
    if (t >= 1) acc += pre[(size_t)(t - 1) * ldp + c] * wc4[2];
    acc += pre[(size_t)t * ldp + c] * wc4[3];
    out[(size_t)t * C + c] = siluf(acc);
}

// ---------------- beta / g projections (f32, exact) ----------------
__global__ __launch_bounds__(256) void beta_g(const float* __restrict__ X,
                                              const float* __restrict__ Wb, const float* __restrict__ Wa,
                                              const float* __restrict__ A_log, const float* __restrict__ dtb,
                                              float* __restrict__ bvec, float* __restrict__ gvec) {
    int t = blockIdx.x;
    int tid = threadIdx.x;
    int s = tid >> 5, c = tid & 31;
    float acc = 0.f;
    const float* xr = X + (size_t)t * HIDN;
    for (int k = s; k < HIDN; k += 8) {
        float xv = xr[k];
        float wv = (c < 16) ? Wb[(size_t)k * 16 + c] : Wa[(size_t)k * 16 + (c - 16)];
        acc += xv * wv;
    }
    __shared__ float red[8][32];
    red[s][c] = acc;
    __syncthreads();
    if (s == 0) {
        float tot = 0.f;
#pragma unroll
        for (int i = 0; i < 8; ++i) tot += red[i][c];
        if (c < 16) {
            bvec[(size_t)t * 16 + c] = 2.f / (1.f + expf(-tot));
        } else {
            int hh = c - 16;
            float a = tot + dtb[hh];
            float sp = (a > 20.f) ? a : log1pf(expf(a));
            gvec[(size_t)t * 16 + hh] = -expf(A_log[hh]) * sp;
        }
    }
}

// ---------------- phase 1: per (chunk, head) WY-transform prep ----------------
__global__ __launch_bounds__(256) void phase1(const float* __restrict__ qpost, const float* __restrict__ kpost,
                                              const float* __restrict__ vpost, const float* __restrict__ gvec,
                                              const float* __restrict__ bvec,
                                              float* __restrict__ u_ws, float* __restrict__ w_ws,
                                              float* __restrict__ qg_ws, float* __restrict__ kd_ws,
                                              float* __restrict__ at_ws, float* __restrict__ gl_ws) {
    int n = blockIdx.x, h = blockIdx.y;
    int t0 = n * CHUNKN;
    int tid = threadIdx.x;
    __shared__ float k_s[64][97];
    __shared__ float A_s[64][64];
    __shared__ float U_s[64][193];
    __shared__ float gc_s[64], bc_s[64], gr_s[64], nrm_s[64];

    if (tid < 64) {
        gr_s[tid] = gvec[(size_t)(t0 + tid) * HVN + h];
        bc_s[tid] = bvec[(size_t)(t0 + tid) * HVN + h];
    }
    __syncthreads();
    if (tid < 64) {
        float sacc = 0.f;
        for (int j = 0; j <= tid; ++j) sacc += gr_s[j];
        gc_s[tid] = sacc;
    }
    // load k, l2norm in place
    for (int idx = tid; idx < 64 * 96; idx += 256) {
        int r = idx / 96, cc = idx % 96;
        k_s[r][cc] = kpost[(size_t)(t0 + r) * KDIMN + h * DKN + cc];
    }
    __syncthreads();
    if (tid < 64) {
        float ss = 0.f;
        for (int d = 0; d < 96; ++d) { float kv = k_s[tid][d]; ss += kv * kv; }
        nrm_s[tid] = rsqrtf(ss + EPSF);
    }
    __syncthreads();
    for (int idx = tid; idx < 64 * 96; idx += 256) {
        int r = idx / 96, cc = idx % 96;
        k_s[r][cc] *= nrm_s[r];
    }
    __syncthreads();
    // A_ij = -beta_i * exp(gc_i - gc_j) * (k_i . k_j), strictly lower
    for (int idx = tid; idx < 64 * 64; idx += 256) {
        int r = idx >> 6, cc = idx & 63;
        float aval = 0.f;
        if (r > cc) {
            float dot = 0.f;
            for (int d = 0; d < 96; ++d) dot += k_s[r][d] * k_s[cc][d];
            aval = -bc_s[r] * expf(gc_s[r] - gc_s[cc]) * dot;
        }
        A_s[r][cc] = aval;
    }
    // u = (I-A)^{-1} (v*beta): forward substitution in U_s[.][0..191]
    for (int idx = tid; idx < 64 * 192; idx += 256) {
        int r = idx / 192, cc = idx % 192;
        U_s[r][cc] = vpost[(size_t)(t0 + r) * VDIMN + h * DVN + cc] * bc_s[r];
    }
    __syncthreads();
    for (int i = 1; i < 64; ++i) {
        if (tid < 192) {
            float a2 = 0.f;
            for (int j = 0; j < i; ++j) a2 += A_s[i][j] * U_s[j][tid];
            U_s[i][tid] += a2;
        }
        __syncthreads();
    }
    size_t base = (size_t)(h * NCHUNK + n);
    float* u_out = u_ws + base * 64 * 192;
    for (int idx = tid; idx < 64 * 192; idx += 256) u_out[idx] = U_s[idx / 192][idx % 192];
    __syncthreads();
    // w = (I-A)^{-1} (k*beta*exp(gc)): substitution on cols 0..95
    for (int idx = tid; idx < 64 * 96; idx += 256) {
        int r = idx / 96, cc = idx % 96;
        U_s[r][cc] = k_s[r][cc] * bc_s[r] * expf(gc_s[r]);
    }
    __syncthreads();
    for (int i = 1; i < 64; ++i) {
        if (tid < 96) {
            float a2 = 0.f;
            for (int j = 0; j < i; ++j) a2 += A_s[i][j] * U_s[j][tid];
            U_s[i][tid] += a2;
        }
        __syncthreads();
    }
    float* w_out = w_ws + base * 64 * 96;
    for (int idx = tid; idx < 64 * 96; idx += 256) w_out[idx] = U_s[idx / 96][idx % 96];
    __syncthreads();
    // q into U_s cols 96..191, l2norm * 96^-0.5
    for (int idx = tid; idx < 64 * 96; idx += 256) {
        int r = idx / 96, cc = idx % 96;
        U_s[r][96 + cc] = qpost[(size_t)(t0 + r) * KDIMN + h * DKN + cc];
    }
    __syncthreads();
    if (tid < 64) {
        float ss = 0.f;
        for (int d = 0; d < 96; ++d) { float qv = U_s[tid][96 + d]; ss += qv * qv; }
        nrm_s[tid] = rsqrtf(ss + EPSF) * 0.10206207261596577f;
    }
    __syncthreads();
    for (int idx = tid; idx < 64 * 96; idx += 256) {
        int r = idx / 96, cc = idx % 96;
        U_s[r][96 + cc] *= nrm_s[r];
    }
    __syncthreads();
    float gl = gc_s[63];
    // attn = (q k^T) * exp(gc_i - gc_j), lower incl diag
    float* at_out = at_ws + base * 64 * 64;
    for (int idx = tid; idx < 64 * 64; idx += 256) {
        int r = idx >> 6, cc = idx & 63;
        float aval = 0.f;
        if (r >= cc) {
            float dot = 0.f;
            for (int d = 0; d < 96; ++d) dot += U_s[r][96 + d] * k_s[cc][d];
            aval = expf(gc_s[r] - gc_s[cc]) * dot;
        }
        at_out[idx] = aval;
    }
    float* qg_out = qg_ws + base * 64 * 96;
    float* kd_out = kd_ws + base * 64 * 96;
    for (int idx = tid; idx < 64 * 96; idx += 256) {
        int r = idx / 96, cc = idx % 96;
        qg_out[idx] = U_s[r][96 + cc] * expf(gc_s[r]);
        kd_out[idx] = k_s[r][cc] * expf(gl - gc_s[r]);
    }
    if (tid == 0) gl_ws[base] = gl;
}

// ---------------- phase 2: sequential chunk scan, per (head, dv-slice) ----------------
#define NSL 12
__global__ __launch_bounds__(256) void phase2(const float* __restrict__ u_ws, const float* __restrict__ w_ws,
                                              const float* __restrict__ qg_ws, const float* __restrict__ kd_ws,
                                              const float* __restrict__ at_ws, const float* __restrict__ gl_ws,
                                              float* __restrict__ o_ws) {
    int sl = blockIdx.x, h = blockIdx.y;
    int c0 = sl * NSL;
    int tid = threadIdx.x;
    __shared__ float S_s[96][NSL + 1];
    __shared__ float w_s[64][97];
    __shared__ float qg_s[64][97];
    __shared__ float kd_s[64][97];
    __shared__ float at_s[64][65];
    __shared__ float u_s[64][NSL + 1];
    __shared__ float vn_s[64][NSL + 1];
    for (int idx = tid; idx < 96 * NSL; idx += 256) S_s[idx / NSL][idx % NSL] = 0.f;
    __syncthreads();
    for (int n = 0; n < NCHUNK; ++n) {
        size_t base = (size_t)(h * NCHUNK + n);
        const float* wp = w_ws + base * 64 * 96;
        const float* qgp = qg_ws + base * 64 * 96;
        const float* kdp = kd_ws + base * 64 * 96;
        const float* ap = at_ws + base * 64 * 64;
        const float* up = u_ws + base * 64 * 192;
        for (int idx = tid; idx < 64 * 96; idx += 256) {
            int r = idx / 96, d = idx % 96;
            w_s[r][d] = wp[idx];
            qg_s[r][d] = qgp[idx];
            kd_s[r][d] = kdp[idx];
        }
        for (int idx = tid; idx < 64 * 64; idx += 256) at_s[idx >> 6][idx & 63] = ap[idx];
        for (int idx = tid; idx < 64 * NSL; idx += 256) {
            int r = idx / NSL, cc = idx % NSL;
            u_s[r][cc] = up[r * 192 + c0 + cc];
        }
        float egl = expf(gl_ws[base]);
        __syncthreads();
        // v_new = u - w @ S
        for (int idx = tid; idx < 64 * NSL; idx += 256) {
            int r = idx / NSL, cc = idx % NSL;
            float acc = u_s[r][cc];
            for (int d = 0; d < 96; ++d) acc -= w_s[r][d] * S_s[d][cc];
            vn_s[r][cc] = acc;
        }
        __syncthreads();
        // o = qg @ S + attn @ v_new
        int t0 = n * CHUNKN;
        for (int idx = tid; idx < 64 * NSL; idx += 256) {
            int r = idx / NSL, cc = idx % NSL;
            float acc = 0.f;
            for (int d = 0; d < 96; ++d) acc += qg_s[r][d] * S_s[d][cc];
            for (int j = 0; j < 64; ++j) acc += at_s[r][j] * vn_s[j][cc];
            o_ws[(size_t)(t0 + r) * VDIMN + h * DVN + c0 + cc] = acc;
        }
        __syncthreads();
        // S = e^gl * S + kd^T @ v_new
        for (int idx = tid; idx < 96 * NSL; idx += 256) {
            int d = idx / NSL, cc = idx % NSL;
            float acc = egl * S_s[d][cc];
            for (int r = 0; r < 64; ++r) acc += kd_s[r][d] * vn_s[r][cc];
            S_s[d][cc] = acc;
        }
        __syncthreads();
    }
}

// ---------------- gate (SiLU) + RMSNorm -> bf16 ----------------
__global__ __launch_bounds__(64) void gate_norm(const float* __restrict__ o_ws, const float* __restrict__ Cproj,
                                                const float* __restrict__ nw, unsigned short* __restrict__ obf) {
    int b = blockIdx.x;
    int t = b >> 4, h = b & 15;
    int lane = threadIdx.x;
    float x[3];
    float ss = 0.f;
    size_t ob = (size_t)t * VDIMN + h * DVN;
    size_t gb = (size_t)t * NPROJ + 6144 + h * DVN;
    for (int j = 0; j < 3; ++j) {
        int d = j * 64 + lane;
        float ov = o_ws[ob + d];
        float gv = Cproj[gb + d];
        float xv = ov * siluf(gv);
        x[j] = xv;
        ss += xv * xv;
    }
    for (int off = 32; off > 0; off >>= 1) ss += __shfl_xor(ss, off, 64);
    float r = rsqrtf(ss * (1.f / 192.f) + EPSF);
    for (int j = 0; j < 3; ++j) {
        int d = j * 64 + lane;
        obf[ob + d] = f2bf(x[j] * r * nw[d]);
    }
}

extern "C" void kernel_launch(void* const* d_in, const int* in_sizes, int n_in,
                              void* d_out, int out_size, void* d_ws, size_t ws_size,
                              hipStream_t stream) {
    (void)in_sizes; (void)n_in; (void)out_size;
    const float* X    = (const float*)d_in[0];
    const float* Wq   = (const float*)d_in[1];
    const float* Wk   = (const float*)d_in[2];
    const float* Wv   = (const float*)d_in[3];
    const float* Wb   = (const float*)d_in[4];
    const float* Wa   = (const float*)d_in[5];
    const float* Wg   = (const float*)d_in[6];
    const float* Wo   = (const float*)d_in[7];
    const float* cq   = (const float*)d_in[8];
    const float* ck   = (const float*)d_in[9];
    const float* cv   = (const float*)d_in[10];
    const float* Alog = (const float*)d_in[11];
    const float* dtb  = (const float*)d_in[12];
    const float* nw   = (const float*)d_in[13];

    // workspace layout (bytes)
    const size_t OFF_XBF   = 0;                       // 2048*2048*2    = 8,388,608
    const size_t OFF_WALLT = 8388608;                 // 9216*2048*2    = 37,748,736
    const size_t OFF_WOT   = 46137344;                // 2048*3072*2    = 12,582,912
    const size_t OFF_CPROJ = 58720256;                // 2048*9216*4    = 75,497,472
    const size_t OFF_QPOST = 134217728;               // 2048*1536*4    = 12,582,912
    const size_t OFF_KPOST = 146800640;               // 2048*1536*4
    const size_t OFF_VPOST = 159383552;               // 2048*3072*4    = 25,165,824
    const size_t OFF_GVEC  = 184549376;               // 2048*16*4
    const size_t OFF_BVEC  = 184680448;
    const size_t OFF_U     = 184811520;               // 16*32*64*192*4 = 25,165,824
    const size_t OFF_W     = 209977344;               // 16*32*64*96*4
    const size_t OFF_QG    = 222560256;
    const size_t OFF_KD    = 235143168;
    const size_t OFF_AT    = 247726080;               // 16*32*64*64*4  = 8,388,608
    const size_t OFF_GL    = 256114688;               // 2048*4 pad
    const size_t OFF_O     = OFF_QPOST;               // alias: qpost+kpost dead after phase1
    const size_t OFF_OBF   = OFF_VPOST;               // alias: vpost dead after phase1
    const size_t NEEDED    = 256114688 + 8192;
    if (ws_size < NEEDED) return; // fail loudly (output stays zero)

    char* ws = (char*)d_ws;
    unsigned short* Xbf   = (unsigned short*)(ws + OFF_XBF);
    unsigned short* WallT = (unsigned short*)(ws + OFF_WALLT);
    unsigned short* WoT   = (unsigned short*)(ws + OFF_WOT);
    float* Cproj = (float*)(ws + OFF_CPROJ);
    float* qpost = (float*)(ws + OFF_QPOST);
    float* kpost = (float*)(ws + OFF_KPOST);
    float* vpost = (float*)(ws + OFF_VPOST);
    float* gvec  = (float*)(ws + OFF_GVEC);
    float* bvec  = (float*)(ws + OFF_BVEC);
    float* u_ws  = (float*)(ws + OFF_U);
    float* w_ws  = (float*)(ws + OFF_W);
    float* qg_ws = (float*)(ws + OFF_QG);
    float* kd_ws = (float*)(ws + OFF_KD);
    float* at_ws = (float*)(ws + OFF_AT);
    float* gl_ws = (float*)(ws + OFF_GL);
    float* o_ws  = (float*)(ws + OFF_O);
    unsigned short* obf = (unsigned short*)(ws + OFF_OBF);

    // 1. casts
    cast_f32_bf16<<<4096, 256, 0, stream>>>(X, Xbf, 2048 * 2048);
    dim3 tb(64, 4);
    transpose_cast<<<dim3(1536 / 64, 2048 / 64), tb, 0, stream>>>(Wq, WallT, 2048, 1536);
    transpose_cast<<<dim3(1536 / 64, 2048 / 64), tb, 0, stream>>>(Wk, WallT + (size_t)1536 * 2048, 2048, 1536);
    transpose_cast<<<dim3(3072 / 64, 2048 / 64), tb, 0, stream>>>(Wv, WallT + (size_t)3072 * 2048, 2048, 3072);
    transpose_cast<<<dim3(3072 / 64, 2048 / 64), tb, 0, stream>>>(Wg, WallT + (size_t)6144 * 2048, 2048, 3072);
    transpose_cast<<<dim3(2048 / 64, 3072 / 64), tb, 0, stream>>>(Wo, WoT, 3072, 2048);

    // 2. fused projection GEMM: Cproj[2048][9216] = Xbf @ WallT^T
    gemm_bt<<<dim3(9216 / 128, 2048 / 128), 256, 0, stream>>>(Xbf, WallT, Cproj, 2048, 9216, 2048);

    // 3. conv + silu (q,k,v), beta/g
    conv_silu<<<dim3(6, T_LEN), 256, 0, stream>>>(Cproj + 0, NPROJ, cq, qpost, KDIMN);
    conv_silu<<<dim3(6, T_LEN), 256, 0, stream>>>(Cproj + 1536, NPROJ, ck, kpost, KDIMN);
    conv_silu<<<dim3(12, T_LEN), 256, 0, stream>>>(Cproj + 3072, NPROJ, cv, vpost, VDIMN);
    beta_g<<<T_LEN, 256, 0, stream>>>(X, Wb, Wa, Alog, dtb, bvec, gvec);

    // 4. delta-rule scan
    phase1<<<dim3(NCHUNK, HVN), 256, 0, stream>>>(qpost, kpost, vpost, gvec, bvec,
                                                  u_ws, w_ws, qg_ws, kd_ws, at_ws, gl_ws);
    phase2<<<dim3(192 / NSL, HVN), 256, 0, stream>>>(u_ws, w_ws, qg_ws, kd_ws, at_ws, gl_ws, o_ws);

    // 5. gate + rmsnorm -> bf16
    gate_norm<<<T_LEN * HVN, 64, 0, stream>>>(o_ws, Cproj, nw, obf);

    // 6. output GEMM: d_out[2048][2048] = obf @ WoT^T
    gemm_bt<<<dim3(2048 / 128, 2048 / 128), 256, 0, stream>>>(obf, WoT, (float*)d_out, 2048, 2048, 3072);
}

// Round 2
// 845.589 us; speedup vs baseline: 1.4701x; 1.4701x over previous
//
#include <hip/hip_runtime.h>
#include <math.h>

#define T_LEN 2048
#define HIDN  2048
#define HKN   16
#define DKN   96
#define HVN   16
#define DVN   192
#define KDIMN 1536
#define VDIMN 3072
#define QKVD  6144   // q(1536)+k(1536)+v(3072)
#define CHUNKN 64
#define NCHUNK 32
#define EPSF 1e-6f

typedef __attribute__((ext_vector_type(8))) short short8;
typedef __attribute__((ext_vector_type(4))) float f32x4;

__device__ __forceinline__ unsigned short f2bf(float f) {
    unsigned int u = __float_as_uint(f);
    unsigned int r = (u + 0x7FFFu + ((u >> 16) & 1u)) >> 16;
    return (unsigned short)r;
}
__device__ __forceinline__ float siluf(float x) { return x / (1.f + expf(-x)); }

__device__ __forceinline__ void gld_lds16(const void* g, void* l) {
    __builtin_amdgcn_global_load_lds((const __attribute__((address_space(1))) unsigned int*)g,
                                     (__attribute__((address_space(3))) unsigned int*)l, 16, 0, 0);
}

// ---------------- cast f32 -> bf16 (4/thread) ----------------
__global__ void cast_f32_bf16(const float* __restrict__ in, unsigned short* __restrict__ out, int n) {
    int i = (blockIdx.x * blockDim.x + threadIdx.x) * 4;
    if (i >= n) return;
    float4 v = *(const float4*)(in + i);
    ushort4 o;
    o.x = f2bf(v.x); o.y = f2bf(v.y); o.z = f2bf(v.z); o.w = f2bf(v.w);
    *(ushort4*)(out + i) = o;
}

// ---------------- transpose + cast: W[K][N] -> Wt[N][K] bf16 ----------------
__global__ void transpose_cast(const float* __restrict__ W, unsigned short* __restrict__ Wt,
                               int K, int N) {
    __shared__ float tile[64][65];
    int k0 = blockIdx.y * 64, n0 = blockIdx.x * 64;
    int tx = threadIdx.x, ty = threadIdx.y; // (64,4)
    for (int r = ty; r < 64; r += 4) tile[r][tx] = W[(size_t)(k0 + r) * N + n0 + tx];
    __syncthreads();
    for (int r = ty; r < 64; r += 4) Wt[(size_t)(n0 + r) * K + k0 + tx] = f2bf(tile[tx][r]);
}

// ---------------- bf16 MFMA GEMM: C[M][N] f32 = A[M][K] @ Bt[N][K]^T ----------------
// 128x128 tile, 4 waves (2x2), each wave 64x64 via 4x4 frags of 16x16x32, BK=32.
// Staging via global_load_lds width=16 (LDS layout is linear in lane order).
__global__ __launch_bounds__(256) void gemm_bt(const unsigned short* __restrict__ A,
                                               const unsigned short* __restrict__ Bt,
                                               float* __restrict__ C, int M, int N, int K) {
    __shared__ __align__(16) unsigned short As[128 * 32];
    __shared__ __align__(16) unsigned short Bs[128 * 32];
    int tid = threadIdx.x;
    int wave = tid >> 6, lane = tid & 63;
    int bm = blockIdx.y, bn = blockIdx.x;
    f32x4 acc[4][4] = {};
    int wr = wave >> 1, wc = wave & 1;
    int rstage = wave * 32 + (lane >> 2);      // tile row for staging (e=0)
    int cstage = (lane & 3) * 8;               // k-offset within BK (elements)
    const size_t a_row0 = (size_t)bm * 128;
    const size_t b_row0 = (size_t)bn * 128;
    int row_a[4], row_b[4];
#pragma unroll
    for (int i = 0; i < 4; ++i) {
        row_a[i] = wr * 64 + i * 16 + (lane & 15);
        row_b[i] = wc * 64 + i * 16 + (lane & 15);
    }
    int koff = (lane >> 4) * 8;
    unsigned short* as_base = As + wave * 1024;
    unsigned short* bs_base = Bs + wave * 1024;
    for (int k0 = 0; k0 < K; k0 += 32) {
        const unsigned short* ga = A + (a_row0 + rstage) * (size_t)K + k0 + cstage;
        const unsigned short* gb = Bt + (b_row0 + rstage) * (size_t)K + k0 + cstage;
        gld_lds16(ga, as_base);
        gld_lds16(ga + (size_t)16 * K, as_base + 512);
        gld_lds16(gb, bs_base);
        gld_lds16(gb + (size_t)16 * K, bs_base + 512);
        __syncthreads();
        short8 af[4], bfr[4];
#pragma unroll
        for (int mi = 0; mi < 4; ++mi) af[mi] = *(const short8*)(As + row_a[mi] * 32 + koff);
#pragma unroll
        for (int ni = 0; ni < 4; ++ni) bfr[ni] = *(const short8*)(Bs + row_b[ni] * 32 + koff);
#pragma unroll
        for (int mi = 0; mi < 4; ++mi)
#pragma unroll
            for (int ni = 0; ni < 4; ++ni)
                acc[mi][ni] = __builtin_amdgcn_mfma_f32_16x16x32_bf16(af[mi], bfr[ni], acc[mi][ni], 0, 0, 0);
        __syncthreads();
    }
#pragma unroll
    for (int mi = 0; mi < 4; ++mi) {
        int rbase = bm * 128 + wr * 64 + mi * 16 + (lane >> 4) * 4;
#pragma unroll
        for (int ni = 0; ni < 4; ++ni) {
            int col = bn * 128 + wc * 64 + ni * 16 + (lane & 15);
#pragma unroll
            for (int j = 0; j < 4; ++j)
                C[(size_t)(rbase + j) * N + col] = acc[mi][ni][j];
        }
    }
}

// ---------------- causal depthwise conv(K=4) + SiLU ----------------
__global__ void conv_silu(const float* __restrict__ pre, int ldp,
                          const float* __restrict__ wconv, float* __restrict__ out, int C) {
    int c = blockIdx.x * blockDim.x + threadIdx.x;
    int t = blockIdx.y;
    if (c >= C) return;
    const float* wc4 = wconv + (size_t)c * 4;
    float acc = 0.f;
    if (t >= 3) acc += pre[(size_t)(t - 3) * ldp + c] * wc4[0];
    if (t >= 2) acc += pre[(size_t)(t - 2) * ldp + c] * wc4[1];
    if (t >= 1) acc += pre[(size_t)(t - 1) * ldp + c] * wc4[2];
    acc += pre[(size_t)t * ldp + c] * wc4[3];
    out[(size_t)t * C + c] = siluf(acc);
}

// ---------------- beta / g projections (f32, exact) ----------------
__global__ __launch_bounds__(256) void beta_g(const float* __restrict__ X,
                                              const float* __restrict__ Wb, const float* __restrict__ Wa,
                                              const float* __restrict__ A_log, const float* __restrict__ dtb,
                                              float* __restrict__ bvec, float* __restrict__ gvec) {
    int t = blockIdx.x;
    int tid = threadIdx.x;
    int s = tid >> 5, c = tid & 31;
    float acc = 0.f;
    const float* xr = X + (size_t)t * HIDN;
    for (int k = s; k < HIDN; k += 8) {
        float xv = xr[k];
        float wv = (c < 16) ? Wb[(size_t)k * 16 + c] : Wa[(size_t)k * 16 + (c - 16)];
        acc += xv * wv;
    }
    __shared__ float red[8][32];
    red[s][c] = acc;
    __syncthreads();
    if (s == 0) {
        float tot = 0.f;
#pragma unroll
        for (int i = 0; i < 8; ++i) tot += red[i][c];
        if (c < 16) {
            bvec[(size_t)t * 16 + c] = 2.f / (1.f + expf(-tot));
        } else {
            int hh = c - 16;
            float a = tot + dtb[hh];
            float sp = (a > 20.f) ? a : log1pf(expf(a));
            gvec[(size_t)t * 16 + hh] = -expf(A_log[hh]) * sp;
        }
    }
}

// ---------------- phase 1: per (chunk, head) WY-transform prep ----------------
__global__ __launch_bounds__(256) void phase1(const float* __restrict__ qpost, const float* __restrict__ kpost,
                                              const float* __restrict__ vpost, const float* __restrict__ gvec,
                                              const float* __restrict__ bvec,
                                              float* __restrict__ u_ws, float* __restrict__ w_ws,
                                              float* __restrict__ qg_ws, float* __restrict__ kd_ws,
                                              float* __restrict__ at_ws, float* __restrict__ gl_ws) {
    int n = blockIdx.x, h = blockIdx.y;
    int t0 = n * CHUNKN;
    int tid = threadIdx.x;
    __shared__ float k_s[64][97];
    __shared__ float A_s[64][64];
    __shared__ float U_s[64][193];
    __shared__ float gc_s[64], bc_s[64], gr_s[64], nrm_s[64];

    if (tid < 64) {
        gr_s[tid] = gvec[(size_t)(t0 + tid) * HVN + h];
        bc_s[tid] = bvec[(size_t)(t0 + tid) * HVN + h];
    }
    __syncthreads();
    if (tid < 64) {
        float sacc = 0.f;
        for (int j = 0; j <= tid; ++j) sacc += gr_s[j];
        gc_s[tid] = sacc;
    }
    for (int idx = tid; idx < 64 * 96; idx += 256) {
        int r = idx / 96, cc = idx % 96;
        k_s[r][cc] = kpost[(size_t)(t0 + r) * KDIMN + h * DKN + cc];
    }
    __syncthreads();
    if (tid < 64) {
        float ss = 0.f;
        for (int d = 0; d < 96; ++d) { float kv = k_s[tid][d]; ss += kv * kv; }
        nrm_s[tid] = rsqrtf(ss + EPSF);
    }
    __syncthreads();
    for (int idx = tid; idx < 64 * 96; idx += 256) {
        int r = idx / 96, cc = idx % 96;
        k_s[r][cc] *= nrm_s[r];
    }
    __syncthreads();
    for (int idx = tid; idx < 64 * 64; idx += 256) {
        int r = idx >> 6, cc = idx & 63;
        float aval = 0.f;
        if (r > cc) {
            float dot = 0.f;
            for (int d = 0; d < 96; ++d) dot += k_s[r][d] * k_s[cc][d];
            aval = -bc_s[r] * expf(gc_s[r] - gc_s[cc]) * dot;
        }
        A_s[r][cc] = aval;
    }
    for (int idx = tid; idx < 64 * 192; idx += 256) {
        int r = idx / 192, cc = idx % 192;
        U_s[r][cc] = vpost[(size_t)(t0 + r) * VDIMN + h * DVN + cc] * bc_s[r];
    }
    __syncthreads();
    for (int i = 1; i < 64; ++i) {
        if (tid < 192) {
            float a2 = 0.f;
            for (int j = 0; j < i; ++j) a2 += A_s[i][j] * U_s[j][tid];
            U_s[i][tid] += a2;
        }
        __syncthreads();
    }
    size_t base = (size_t)(h * NCHUNK + n);
    float* u_out = u_ws + base * 64 * 192;
    for (int idx = tid; idx < 64 * 192; idx += 256) u_out[idx] = U_s[idx / 192][idx % 192];
    __syncthreads();
    for (int idx = tid; idx < 64 * 96; idx += 256) {
        int r = idx / 96, cc = idx % 96;
        U_s[r][cc] = k_s[r][cc] * bc_s[r] * expf(gc_s[r]);
    }
    __syncthreads();
    for (int i = 1; i < 64; ++i) {
        if (tid < 96) {
            float a2 = 0.f;
            for (int j = 0; j < i; ++j) a2 += A_s[i][j] * U_s[j][tid];
            U_s[i][tid] += a2;
        }
        __syncthreads();
    }
    float* w_out = w_ws + base * 64 * 96;
    for (int idx = tid; idx < 64 * 96; idx += 256) w_out[idx] = U_s[idx / 96][idx % 96];
    __syncthreads();
    for (int idx = tid; idx < 64 * 96; idx += 256) {
        int r = idx / 96, cc = idx % 96;
        U_s[r][96 + cc] = qpost[(size_t)(t0 + r) * KDIMN + h * DKN + cc];
    }
    __syncthreads();
    if (tid < 64) {
        float ss = 0.f;
        for (int d = 0; d < 96; ++d) { float qv = U_s[tid][96 + d]; ss += qv * qv; }
        nrm_s[tid] = rsqrtf(ss + EPSF) * 0.10206207261596577f;
    }
    __syncthreads();
    for (int idx = tid; idx < 64 * 96; idx += 256) {
        int r = idx / 96, cc = idx % 96;
        U_s[r][96 + cc] *= nrm_s[r];
    }
    __syncthreads();
    float gl = gc_s[63];
    float* at_out = at_ws + base * 64 * 64;
    for (int idx = tid; idx < 64 * 64; idx += 256) {
        int r = idx >> 6, cc = idx & 63;
        float aval = 0.f;
        if (r >= cc) {
            float dot = 0.f;
            for (int d = 0; d < 96; ++d) dot += U_s[r][96 + d] * k_s[cc][d];
            aval = expf(gc_s[r] - gc_s[cc]) * dot;
        }
        at_out[idx] = aval;
    }
    float* qg_out = qg_ws + base * 64 * 96;
    float* kd_out = kd_ws + base * 64 * 96;
    for (int idx = tid; idx < 64 * 96; idx += 256) {
        int r = idx / 96, cc = idx % 96;
        qg_out[idx] = U_s[r][96 + cc] * expf(gc_s[r]);
        kd_out[idx] = k_s[r][cc] * expf(gl - gc_s[r]);
    }
    if (tid == 0) gl_ws[base] = gl;
}

// ---------------- phase 2a: sequential recurrence only ----------------
// grid (12 slices of 16 cols, 16 heads), 256 threads.
// vnew = u - w@S ; store S_n (pre), vnew ; S = e^gl*S + kd^T@vnew
__global__ __launch_bounds__(256) void phase2a(const float* __restrict__ u_ws, const float* __restrict__ w_ws,
                                               const float* __restrict__ kd_ws, const float* __restrict__ gl_ws,
                                               float* __restrict__ vn_ws, float* __restrict__ s_ws) {
    int sl = blockIdx.x, h = blockIdx.y;
    int c0 = sl * 16;
    int tid = threadIdx.x;
    __shared__ float w_s[64][100];
    __shared__ float kd_s[64][100];
    __shared__ float S_s[96][20];
    __shared__ float vn_s[64][20];
    int r1 = tid >> 2, dg = tid & 3;         // matmul1 role
    int d2 = tid % 96, cq = tid / 96;        // matmul2 role (cq<2 active)
    bool act2 = tid < 192;
    float Sreg[8];
#pragma unroll
    for (int j = 0; j < 8; ++j) Sreg[j] = 0.f;
    for (int idx = tid; idx < 96 * 20; idx += 256) (&S_s[0][0])[idx] = 0.f;
    __syncthreads();
    for (int n = 0; n < NCHUNK; ++n) {
        size_t base = (size_t)(h * NCHUNK + n);
        const float* wp = w_ws + base * (64 * 96);
        const float* kdp = kd_ws + base * (64 * 96);
        const float* up = u_ws + base * (64 * 192);
        float* vnp = vn_ws + base * (64 * 192);
        float* sp = s_ws + base * (96 * 192);
        float egl = expf(gl_ws[base]);
        // issue staging loads (w,kd full; u slice)
        float4 wst[6], kst[6];
#pragma unroll
        for (int j = 0; j < 6; ++j) {
            int f = j * 256 + tid;           // float4 index over 64*96
            wst[j] = ((const float4*)wp)[f];
            kst[j] = ((const float4*)kdp)[f];
        }
        float4 u4 = *(const float4*)(up + (size_t)r1 * 192 + c0 + dg * 4);
        // store pre-chunk state S_n
        if (act2) {
            *(float4*)(sp + (size_t)d2 * 192 + c0 + cq * 8)     = *(float4*)&Sreg[0];
            *(float4*)(sp + (size_t)d2 * 192 + c0 + cq * 8 + 4) = *(float4*)&Sreg[4];
        }
#pragma unroll
        for (int j = 0; j < 6; ++j) {
            int f = j * 256 + tid;
            int rr = f / 24, cc4 = (f % 24) * 4;
            *(float4*)&w_s[rr][cc4] = wst[j];
            *(float4*)&kd_s[rr][cc4] = kst[j];
        }
        __syncthreads();
        // m1: partial sums over d = 4i+dg
        float acc[16];
#pragma unroll
        for (int c = 0; c < 16; ++c) acc[c] = 0.f;
        for (int i = 0; i < 24; ++i) {
            int d = i * 4 + dg;
            float wv = w_s[r1][d];
            float4 s0 = *(const float4*)&S_s[d][0];
            float4 s1 = *(const float4*)&S_s[d][4];
            float4 s2 = *(const float4*)&S_s[d][8];
            float4 s3 = *(const float4*)&S_s[d][12];
            acc[0] += wv * s0.x; acc[1] += wv * s0.y; acc[2] += wv * s0.z; acc[3] += wv * s0.w;
            acc[4] += wv * s1.x; acc[5] += wv * s1.y; acc[6] += wv * s1.z; acc[7] += wv * s1.w;
            acc[8] += wv * s2.x; acc[9] += wv * s2.y; acc[10] += wv * s2.z; acc[11] += wv * s2.w;
            acc[12] += wv * s3.x; acc[13] += wv * s3.y; acc[14] += wv * s3.z; acc[15] += wv * s3.w;
        }
        // reduce-scatter over dg: lane dg ends with cols dg*4..dg*4+3
        bool hi2 = (dg & 2) != 0, hi1 = (dg & 1) != 0;
        float half8[8], fin[4];
#pragma unroll
        for (int j = 0; j < 8; ++j) {
            float mine = hi2 ? acc[8 + j] : acc[j];
            float yours = hi2 ? acc[j] : acc[8 + j];
            half8[j] = mine + __shfl_xor(yours, 2, 64);
        }
#pragma unroll
        for (int j = 0; j < 4; ++j) {
            float mine = hi1 ? half8[4 + j] : half8[j];
            float yours = hi1 ? half8[j] : half8[4 + j];
            fin[j] = mine + __shfl_xor(yours, 1, 64);
        }
        float4 vn4;
        vn4.x = u4.x - fin[0]; vn4.y = u4.y - fin[1]; vn4.z = u4.z - fin[2]; vn4.w = u4.w - fin[3];
        *(float4*)&vn_s[r1][dg * 4] = vn4;
        *(float4*)(vnp + (size_t)r1 * 192 + c0 + dg * 4) = vn4;
        __syncthreads();
        // m2: Snew = egl*S + kd^T @ vnew
        if (act2) {
            float a2[8];
#pragma unroll
            for (int j = 0; j < 8; ++j) a2[j] = 0.f;
            for (int r = 0; r < 64; ++r) {
                float kv = kd_s[r][d2];
                float4 v0 = *(const float4*)&vn_s[r][cq * 8];
                float4 v1 = *(const float4*)&vn_s[r][cq * 8 + 4];
                a2[0] += kv * v0.x; a2[1] += kv * v0.y; a2[2] += kv * v0.z; a2[3] += kv * v0.w;
                a2[4] += kv * v1.x; a2[5] += kv * v1.y; a2[6] += kv * v1.z; a2[7] += kv * v1.w;
            }
#pragma unroll
            for (int j = 0; j < 8; ++j) Sreg[j] = egl * Sreg[j] + a2[j];
            *(float4*)&S_s[d2][cq * 8] = *(float4*)&Sreg[0];
            *(float4*)&S_s[d2][cq * 8 + 4] = *(float4*)&Sreg[4];
        }
        __syncthreads();
    }
}

// ---------------- phase 2b: parallel o = qg@S_n + at@vn ----------------
// grid (NCHUNK, 16h*2colhalf), 384 threads; thread tile 4 rows x 4 cols.
__global__ __launch_bounds__(384) void phase2b(const float* __restrict__ qg_ws, const float* __restrict__ at_ws,
                                               const float* __restrict__ s_ws, const float* __restrict__ vn_ws,
                                               float* __restrict__ o_ws) {
    int n = blockIdx.x;
    int h = blockIdx.y >> 1, ch = blockIdx.y & 1;
    int tid = threadIdx.x;
    int rg = tid / 24, cg = tid % 24;
    __shared__ float qg_s[64][100];
    __shared__ float at_s[64][68];
    size_t base = (size_t)(h * NCHUNK + n);
    const float* qgp = qg_ws + base * (64 * 96);
    const float* ap  = at_ws + base * (64 * 64);
    const float* sp  = s_ws + base * (96 * 192) + ch * 96;
    const float* vnp = vn_ws + base * (64 * 192) + ch * 96;
    for (int f = tid; f < 1536; f += 384) {
        int rr = f / 24, cc = (f % 24) * 4;
        *(float4*)&qg_s[rr][cc] = ((const float4*)qgp)[f];
    }
    for (int f = tid; f < 1024; f += 384) {
        int rr = f / 16, cc = (f % 16) * 4;
        *(float4*)&at_s[rr][cc] = ((const float4*)ap)[f];
    }
    __syncthreads();
    float acc00=0,acc01=0,acc02=0,acc03=0, acc10=0,acc11=0,acc12=0,acc13=0;
    float acc20=0,acc21=0,acc22=0,acc23=0, acc30=0,acc31=0,acc32=0,acc33=0;
    int r0 = rg * 4, cc0 = cg * 4;
#pragma unroll 4
    for (int k = 0; k < 96; ++k) {
        float4 b = *(const float4*)(sp + (size_t)k * 192 + cc0);
        float a0 = qg_s[r0][k], a1 = qg_s[r0 + 1][k], a2 = qg_s[r0 + 2][k], a3 = qg_s[r0 + 3][k];
        acc00 += a0 * b.x; acc01 += a0 * b.y; acc02 += a0 * b.z; acc03 += a0 * b.w;
        acc10 += a1 * b.x; acc11 += a1 * b.y; acc12 += a1 * b.z; acc13 += a1 * b.w;
        acc20 += a2 * b.x; acc21 += a2 * b.y; acc22 += a2 * b.z; acc23 += a2 * b.w;
        acc30 += a3 * b.x; acc31 += a3 * b.y; acc32 += a3 * b.z; acc33 += a3 * b.w;
    }
#pragma unroll 4
    for (int j = 0; j < 64; ++j) {
        float4 b = *(const float4*)(vnp + (size_t)j * 192 + cc0);
        float a0 = at_s[r0][j], a1 = at_s[r0 + 1][j], a2 = at_s[r0 + 2][j], a3 = at_s[r0 + 3][j];
        acc00 += a0 * b.x; acc01 += a0 * b.y; acc02 += a0 * b.z; acc03 += a0 * b.w;
        acc10 += a1 * b.x; acc11 += a1 * b.y; acc12 += a1 * b.z; acc13 += a1 * b.w;
        acc20 += a2 * b.x; acc21 += a2 * b.y; acc22 += a2 * b.z; acc23 += a2 * b.w;
        acc30 += a3 * b.x; acc31 += a3 * b.y; acc32 += a3 * b.z; acc33 += a3 * b.w;
    }
    int t0 = n * CHUNKN;
    size_t ob = (size_t)(t0 + r0) * VDIMN + h * DVN + ch * 96 + cc0;
    *(float4*)(o_ws + ob)             = make_float4(acc00, acc01, acc02, acc03);
    *(float4*)(o_ws + ob + VDIMN)     = make_float4(acc10, acc11, acc12, acc13);
    *(float4*)(o_ws + ob + 2 * VDIMN) = make_float4(acc20, acc21, acc22, acc23);
    *(float4*)(o_ws + ob + 3 * VDIMN) = make_float4(acc30, acc31, acc32, acc33);
}

// ---------------- gate (SiLU) + RMSNorm -> bf16 ----------------
__global__ __launch_bounds__(64) void gate_norm(const float* __restrict__ o_ws, const float* __restrict__ Cgate,
                                                const float* __restrict__ nw, unsigned short* __restrict__ obf) {
    int b = blockIdx.x;
    int t = b >> 4, h = b & 15;
    int lane = threadIdx.x;
    float x[3];
    float ss = 0.f;
    size_t ob = (size_t)t * VDIMN + h * DVN;
    for (int j = 0; j < 3; ++j) {
        int d = j * 64 + lane;
        float ov = o_ws[ob + d];
        float gv = Cgate[ob + d];
        float xv = ov * siluf(gv);
        x[j] = xv;
        ss += xv * xv;
    }
    for (int off = 32; off > 0; off >>= 1) ss += __shfl_xor(ss, off, 64);
    float r = rsqrtf(ss * (1.f / 192.f) + EPSF);
    for (int j = 0; j < 3; ++j) {
        int d = j * 64 + lane;
        obf[ob + d] = f2bf(x[j] * r * nw[d]);
    }
}

extern "C" void kernel_launch(void* const* d_in, const int* in_sizes, int n_in,
                              void* d_out, int out_size, void* d_ws, size_t ws_size,
                              hipStream_t stream) {
    (void)in_sizes; (void)n_in; (void)out_size;
    const float* X    = (const float*)d_in[0];
    const float* Wq   = (const float*)d_in[1];
    const float* Wk   = (const float*)d_in[2];
    const float* Wv   = (const float*)d_in[3];
    const float* Wb   = (const float*)d_in[4];
    const float* Wa   = (const float*)d_in[5];
    const float* Wg   = (const float*)d_in[6];
    const float* Wo   = (const float*)d_in[7];
    const float* cq   = (const float*)d_in[8];
    const float* ck   = (const float*)d_in[9];
    const float* cv   = (const float*)d_in[10];
    const float* Alog = (const float*)d_in[11];
    const float* dtb  = (const float*)d_in[12];
    const float* nw   = (const float*)d_in[13];

    // workspace layout (bytes)
    const size_t OFF_XBF   = 0;                    // 8,388,608   (dead after proj gemms)
    const size_t OFF_WALLT = 8388608;              // 37,748,736
    const size_t OFF_WOT   = 46137344;             // 12,582,912
    const size_t OFF_CQKV  = 58720256;             // 50,331,648  (dead after conv)
    const size_t OFF_CGATE = 109051904;            // 25,165,824
    const size_t OFF_QPOST = 134217728;            // 12,582,912  (dead after phase1)
    const size_t OFF_KPOST = 146800640;            // 12,582,912  (dead after phase1)
    const size_t OFF_VPOST = 159383552;            // 25,165,824  (dead after phase1)
    const size_t OFF_GVEC  = 184549376;            // 131,072
    const size_t OFF_BVEC  = 184680448;            // 131,072
    const size_t OFF_GL    = 184811520;            // 8,192 (pad)
    const size_t OFF_U     = 184819712;            // 25,165,824 (u, then vn in place)
    const size_t OFF_W     = 209985536;            // 12,582,912
    const size_t OFF_QG    = 222568448;            // 12,582,912
    const size_t OFF_KD    = 235151360;            // 12,582,912 -> end 247,734,272
    const size_t OFF_AT    = OFF_XBF;              // alias: 8,388,608 exactly
    const size_t OFF_S     = OFF_CQKV;             // alias: 37,748,736 <= 50,331,648
    const size_t OFF_O     = OFF_QPOST;            // alias: 25,165,824 over qpost+kpost
    const size_t OFF_OBF   = OFF_VPOST;            // alias: 12,582,912
    const size_t NEEDED    = 247734272;
    if (ws_size < NEEDED) return;

    char* ws = (char*)d_ws;
    unsigned short* Xbf   = (unsigned short*)(ws + OFF_XBF);
    unsigned short* WallT = (unsigned short*)(ws + OFF_WALLT);
    unsigned short* WoT   = (unsigned short*)(ws + OFF_WOT);
    float* Cqkv  = (float*)(ws + OFF_CQKV);
    float* Cgate = (float*)(ws + OFF_CGATE);
    float* qpost = (float*)(ws + OFF_QPOST);
    float* kpost = (float*)(ws + OFF_KPOST);
    float* vpost = (float*)(ws + OFF_VPOST);
    float* gvec  = (float*)(ws + OFF_GVEC);
    float* bvec  = (float*)(ws + OFF_BVEC);
    float* gl_ws = (float*)(ws + OFF_GL);
    float* u_ws  = (float*)(ws + OFF_U);
    float* w_ws  = (float*)(ws + OFF_W);
    float* qg_ws = (float*)(ws + OFF_QG);
    float* kd_ws = (float*)(ws + OFF_KD);
    float* at_ws = (float*)(ws + OFF_AT);
    float* s_ws  = (float*)(ws + OFF_S);
    float* o_ws  = (float*)(ws + OFF_O);
    unsigned short* obf = (unsigned short*)(ws + OFF_OBF);

    // 1. casts
    cast_f32_bf16<<<4096, 256, 0, stream>>>(X, Xbf, 2048 * 2048);
    dim3 tb(64, 4);
    transpose_cast<<<dim3(1536 / 64, 2048 / 64), tb, 0, stream>>>(Wq, WallT, 2048, 1536);
    transpose_cast<<<dim3(1536 / 64, 2048 / 64), tb, 0, stream>>>(Wk, WallT + (size_t)1536 * 2048, 2048, 1536);
    transpose_cast<<<dim3(3072 / 64, 2048 / 64), tb, 0, stream>>>(Wv, WallT + (size_t)3072 * 2048, 2048, 3072);
    transpose_cast<<<dim3(3072 / 64, 2048 / 64), tb, 0, stream>>>(Wg, WallT + (size_t)6144 * 2048, 2048, 3072);
    transpose_cast<<<dim3(2048 / 64, 3072 / 64), tb, 0, stream>>>(Wo, WoT, 3072, 2048);

    // 2. projection GEMMs
    gemm_bt<<<dim3(QKVD / 128, 2048 / 128), 256, 0, stream>>>(Xbf, WallT, Cqkv, 2048, QKVD, 2048);
    gemm_bt<<<dim3(VDIMN / 128, 2048 / 128), 256, 0, stream>>>(Xbf, WallT + (size_t)QKVD * 2048, Cgate, 2048, VDIMN, 2048);

    // 3. conv + silu (q,k,v), beta/g
    conv_silu<<<dim3(6, T_LEN), 256, 0, stream>>>(Cqkv + 0, QKVD, cq, qpost, KDIMN);
    conv_silu<<<dim3(6, T_LEN), 256, 0, stream>>>(Cqkv + 1536, QKVD, ck, kpost, KDIMN);
    conv_silu<<<dim3(12, T_LEN), 256, 0, stream>>>(Cqkv + 3072, QKVD, cv, vpost, VDIMN);
    beta_g<<<T_LEN, 256, 0, stream>>>(X, Wb, Wa, Alog, dtb, bvec, gvec);

    // 4. delta-rule scan
    phase1<<<dim3(NCHUNK, HVN), 256, 0, stream>>>(qpost, kpost, vpost, gvec, bvec,
                                                  u_ws, w_ws, qg_ws, kd_ws, at_ws, gl_ws);
    phase2a<<<dim3(12, HVN), 256, 0, stream>>>(u_ws, w_ws, kd_ws, gl_ws, u_ws, s_ws);
    phase2b<<<dim3(NCHUNK, HVN * 2), 384, 0, stream>>>(qg_ws, at_ws, s_ws, u_ws, o_ws);

    // 5. gate + rmsnorm -> bf16
    gate_norm<<<T_LEN * HVN, 64, 0, stream>>>(o_ws, Cgate, nw, obf);

    // 6. output GEMM
    gemm_bt<<<dim3(2048 / 128, 2048 / 128), 256, 0, stream>>>(obf, WoT, (float*)d_out, 2048, 2048, 3072);
}

// Round 3
// 665.897 us; speedup vs baseline: 1.8668x; 1.2698x over previous
//
#include <hip/hip_runtime.h>
#include <math.h>

#define T_LEN 2048
#define HIDN  2048
#define HKN   16
#define DKN   96
#define HVN   16
#define DVN   192
#define KDIMN 1536
#define VDIMN 3072
#define QKVD  6144   // q(1536)+k(1536)+v(3072)
#define CHUNKN 64
#define NCHUNK 32
#define EPSF 1e-6f

typedef __attribute__((ext_vector_type(8))) short short8;
typedef __attribute__((ext_vector_type(4))) float f32x4;

__device__ __forceinline__ unsigned short f2bf(float f) {
    unsigned int u = __float_as_uint(f);
    unsigned int r = (u + 0x7FFFu + ((u >> 16) & 1u)) >> 16;
    return (unsigned short)r;
}
__device__ __forceinline__ float siluf(float x) { return x / (1.f + expf(-x)); }

__device__ __forceinline__ void gld_lds16(const void* g, void* l) {
    __builtin_amdgcn_global_load_lds((const __attribute__((address_space(1))) unsigned int*)g,
                                     (__attribute__((address_space(3))) unsigned int*)l, 16, 0, 0);
}

// ---------------- cast f32 -> bf16 (4/thread) ----------------
__global__ void cast_f32_bf16(const float* __restrict__ in, unsigned short* __restrict__ out, int n) {
    int i = (blockIdx.x * blockDim.x + threadIdx.x) * 4;
    if (i >= n) return;
    float4 v = *(const float4*)(in + i);
    ushort4 o;
    o.x = f2bf(v.x); o.y = f2bf(v.y); o.z = f2bf(v.z); o.w = f2bf(v.w);
    *(ushort4*)(out + i) = o;
}

// ---------------- transpose + cast: W[K][N] -> Wt[N][K] bf16 ----------------
__global__ void transpose_cast(const float* __restrict__ W, unsigned short* __restrict__ Wt,
                               int K, int N) {
    __shared__ float tile[64][65];
    int k0 = blockIdx.y * 64, n0 = blockIdx.x * 64;
    int tx = threadIdx.x, ty = threadIdx.y; // (64,4)
    for (int r = ty; r < 64; r += 4) tile[r][tx] = W[(size_t)(k0 + r) * N + n0 + tx];
    __syncthreads();
    for (int r = ty; r < 64; r += 4) Wt[(size_t)(n0 + r) * K + k0 + tx] = f2bf(tile[tx][r]);
}

// ---------------- bf16 MFMA GEMM: C[M][N] f32 = A[M][K] @ Bt[N][K]^T ----------------
__global__ __launch_bounds__(256) void gemm_bt(const unsigned short* __restrict__ A,
                                               const unsigned short* __restrict__ Bt,
                                               float* __restrict__ C, int M, int N, int K) {
    __shared__ __align__(16) unsigned short As[128 * 32];
    __shared__ __align__(16) unsigned short Bs[128 * 32];
    int tid = threadIdx.x;
    int wave = tid >> 6, lane = tid & 63;
    int bm = blockIdx.y, bn = blockIdx.x;
    f32x4 acc[4][4] = {};
    int wr = wave >> 1, wc = wave & 1;
    int rstage = wave * 32 + (lane >> 2);
    int cstage = (lane & 3) * 8;
    const size_t a_row0 = (size_t)bm * 128;
    const size_t b_row0 = (size_t)bn * 128;
    int row_a[4], row_b[4];
#pragma unroll
    for (int i = 0; i < 4; ++i) {
        row_a[i] = wr * 64 + i * 16 + (lane & 15);
        row_b[i] = wc * 64 + i * 16 + (lane & 15);
    }
    int koff = (lane >> 4) * 8;
    unsigned short* as_base = As + wave * 1024;
    unsigned short* bs_base = Bs + wave * 1024;
    for (int k0 = 0; k0 < K; k0 += 32) {
        const unsigned short* ga = A + (a_row0 + rstage) * (size_t)K + k0 + cstage;
        const unsigned short* gb = Bt + (b_row0 + rstage) * (size_t)K + k0 + cstage;
        gld_lds16(ga, as_base);
        gld_lds16(ga + (size_t)16 * K, as_base + 512);
        gld_lds16(gb, bs_base);
        gld_lds16(gb + (size_t)16 * K, bs_base + 512);
        __syncthreads();
        short8 af[4], bfr[4];
#pragma unroll
        for (int mi = 0; mi < 4; ++mi) af[mi] = *(const short8*)(As + row_a[mi] * 32 + koff);
#pragma unroll
        for (int ni = 0; ni < 4; ++ni) bfr[ni] = *(const short8*)(Bs + row_b[ni] * 32 + koff);
#pragma unroll
        for (int mi = 0; mi < 4; ++mi)
#pragma unroll
            for (int ni = 0; ni < 4; ++ni)
                acc[mi][ni] = __builtin_amdgcn_mfma_f32_16x16x32_bf16(af[mi], bfr[ni], acc[mi][ni], 0, 0, 0);
        __syncthreads();
    }
#pragma unroll
    for (int mi = 0; mi < 4; ++mi) {
        int rbase = bm * 128 + wr * 64 + mi * 16 + (lane >> 4) * 4;
#pragma unroll
        for (int ni = 0; ni < 4; ++ni) {
            int col = bn * 128 + wc * 64 + ni * 16 + (lane & 15);
#pragma unroll
            for (int j = 0; j < 4; ++j)
                C[(size_t)(rbase + j) * N + col] = acc[mi][ni][j];
        }
    }
}

// ---------------- causal depthwise conv(K=4) + SiLU ----------------
__global__ void conv_silu(const float* __restrict__ pre, int ldp,
                          const float* __restrict__ wconv, float* __restrict__ out, int C) {
    int c = blockIdx.x * blockDim.x + threadIdx.x;
    int t = blockIdx.y;
    if (c >= C) return;
    const float* wc4 = wconv + (size_t)c * 4;
    float acc = 0.f;
    if (t >= 3) acc += pre[(size_t)(t - 3) * ldp + c] * wc4[0];
    if (t >= 2) acc += pre[(size_t)(t - 2) * ldp + c] * wc4[1];
    if (t >= 1) acc += pre[(size_t)(t - 1) * ldp + c] * wc4[2];
    acc += pre[(size_t)t * ldp + c] * wc4[3];
    out[(size_t)t * C + c] = siluf(acc);
}

// ---------------- beta / g projections (f32, exact) ----------------
__global__ __launch_bounds__(256) void beta_g(const float* __restrict__ X,
                                              const float* __restrict__ Wb, const float* __restrict__ Wa,
                                              const float* __restrict__ A_log, const float* __restrict__ dtb,
                                              float* __restrict__ bvec, float* __restrict__ gvec) {
    int t = blockIdx.x;
    int tid = threadIdx.x;
    int s = tid >> 5, c = tid & 31;
    float acc = 0.f;
    const float* xr = X + (size_t)t * HIDN;
    for (int k = s; k < HIDN; k += 8) {
        float xv = xr[k];
        float wv = (c < 16) ? Wb[(size_t)k * 16 + c] : Wa[(size_t)k * 16 + (c - 16)];
        acc += xv * wv;
    }
    __shared__ float red[8][32];
    red[s][c] = acc;
    __syncthreads();
    if (s == 0) {
        float tot = 0.f;
#pragma unroll
        for (int i = 0; i < 8; ++i) tot += red[i][c];
        if (c < 16) {
            bvec[(size_t)t * 16 + c] = 2.f / (1.f + expf(-tot));
        } else {
            int hh = c - 16;
            float a = tot + dtb[hh];
            float sp = (a > 20.f) ? a : log1pf(expf(a));
            gvec[(size_t)t * 16 + hh] = -expf(A_log[hh]) * sp;
        }
    }
}

// ---------------- phase 1 (MFMA): per (chunk, head) WY-transform prep ----------------
// A_raw/attn via MFMA; (I-A)^-1 via nilpotent doubling; u/w via T@RHS MFMA.
__global__ __launch_bounds__(256) void phase1_mfma(
    const float* __restrict__ qpost, const float* __restrict__ kpost,
    const float* __restrict__ vpost, const float* __restrict__ gvec,
    const float* __restrict__ bvec,
    float* __restrict__ u_ws, float* __restrict__ w_ws,
    float* __restrict__ qg_ws, float* __restrict__ kd_ws,
    float* __restrict__ at_ws, float* __restrict__ gl_ws) {
    int n = blockIdx.x, h = blockIdx.y;
    int t0 = n * CHUNKN;
    int tid = threadIdx.x;
    int wave = tid >> 6, lane = tid & 63;
    size_t base = (size_t)(h * NCHUNK + n);

    __shared__ __align__(16) unsigned short QKb[128 * 104]; // Kn rows 0..63, Qn rows 64..127
    __shared__ __align__(16) unsigned short Ab[64 * 104];
    __shared__ __align__(16) unsigned short Atb[64 * 104];
    __shared__ __align__(16) unsigned short Pb[64 * 104];
    __shared__ __align__(16) unsigned short Ptb[64 * 104];
    __shared__ float Pf[64 * 68];
    __shared__ __align__(16) unsigned short RHSw[96 * 72];  // (k*beta*e^gc)^T [d][t]
    __shared__ __align__(16) unsigned short RHSv[192 * 72]; // (v*beta)^T [d][t]
    __shared__ float gr_s[64], gc_s[64], be_s[64];

    if (tid < 64) {
        gr_s[tid] = gvec[(size_t)(t0 + tid) * HVN + h];
        be_s[tid] = bvec[(size_t)(t0 + tid) * HVN + h];
    }
    __syncthreads();
    if (tid < 64) {
        float sacc = 0.f;
        for (int j = 0; j <= tid; ++j) sacc += gr_s[j];
        gc_s[tid] = sacc;
    }
    __syncthreads();
    float gl = gc_s[63];

    int r = tid >> 2, sub = tid & 3;
    // ---- k: load, l2norm, write Kn(bf16), kd_ws, RHSw ----
    {
        const float* kp = kpost + (size_t)(t0 + r) * KDIMN + h * DKN + sub * 24;
        float kreg[24];
        float ss = 0.f;
#pragma unroll
        for (int i = 0; i < 6; ++i) {
            float4 v = *(const float4*)(kp + i * 4);
            kreg[i * 4 + 0] = v.x; kreg[i * 4 + 1] = v.y; kreg[i * 4 + 2] = v.z; kreg[i * 4 + 3] = v.w;
            ss += v.x * v.x + v.y * v.y + v.z * v.z + v.w * v.w;
        }
        ss += __shfl_xor(ss, 1, 64);
        ss += __shfl_xor(ss, 2, 64);
        float nrm = rsqrtf(ss + EPSF);
        float gcr = gc_s[r];
        float egl = expf(gl - gcr);
        float ebg = be_s[r] * expf(gcr);
        float* kdp = kd_ws + base * (64 * 96) + r * 96 + sub * 24;
#pragma unroll
        for (int i = 0; i < 24; ++i) {
            float kn = kreg[i] * nrm;
            QKb[r * 104 + sub * 24 + i] = f2bf(kn);
            kdp[i] = kn * egl;
            RHSw[(sub * 24 + i) * 72 + r] = f2bf(kn * ebg);
        }
    }
    // ---- q: load, l2norm*dk^-0.5, write Qn(bf16), qg_ws ----
    {
        const float* qp = qpost + (size_t)(t0 + r) * KDIMN + h * DKN + sub * 24;
        float qreg[24];
        float ss = 0.f;
#pragma unroll
        for (int i = 0; i < 6; ++i) {
            float4 v = *(const float4*)(qp + i * 4);
            qreg[i * 4 + 0] = v.x; qreg[i * 4 + 1] = v.y; qreg[i * 4 + 2] = v.z; qreg[i * 4 + 3] = v.w;
            ss += v.x * v.x + v.y * v.y + v.z * v.z + v.w * v.w;
        }
        ss += __shfl_xor(ss, 1, 64);
        ss += __shfl_xor(ss, 2, 64);
        float nrm = rsqrtf(ss + EPSF) * 0.10206207261596577f;
        float eg = expf(gc_s[r]);
        float* qgp = qg_ws + base * (64 * 96) + r * 96 + sub * 24;
#pragma unroll
        for (int i = 0; i < 24; ++i) {
            float qn = qreg[i] * nrm;
            QKb[(64 + r) * 104 + sub * 24 + i] = f2bf(qn);
            qgp[i] = qn * eg;
        }
    }
    // ---- v: stage RHSv = (v*beta)^T bf16 ----
    {
        const float* vp = vpost + (size_t)(t0 + r) * VDIMN + h * DVN + sub * 48;
        float ber = be_s[r];
#pragma unroll
        for (int i = 0; i < 12; ++i) {
            float4 v = *(const float4*)(vp + i * 4);
            int d = sub * 48 + i * 4;
            RHSv[(d + 0) * 72 + r] = f2bf(v.x * ber);
            RHSv[(d + 1) * 72 + r] = f2bf(v.y * ber);
            RHSv[(d + 2) * 72 + r] = f2bf(v.z * ber);
            RHSv[(d + 3) * 72 + r] = f2bf(v.w * ber);
        }
    }
    __syncthreads();

    // ---- MFMA1: [Kn;Qn] @ Kn^T -> A_raw (rows 0..63), attn_raw (rows 64..127) ----
    {
        f32x4 acc1[2][4] = {};
#pragma unroll
        for (int ks = 0; ks < 3; ++ks) {
            int ko = ks * 32 + (lane >> 4) * 8;
            short8 af[2], bfv[4];
#pragma unroll
            for (int rt2 = 0; rt2 < 2; ++rt2)
                af[rt2] = *(const short8*)&QKb[(wave * 32 + rt2 * 16 + (lane & 15)) * 104 + ko];
#pragma unroll
            for (int ct = 0; ct < 4; ++ct)
                bfv[ct] = *(const short8*)&QKb[(ct * 16 + (lane & 15)) * 104 + ko];
#pragma unroll
            for (int rt2 = 0; rt2 < 2; ++rt2)
#pragma unroll
                for (int ct = 0; ct < 4; ++ct)
                    acc1[rt2][ct] = __builtin_amdgcn_mfma_f32_16x16x32_bf16(af[rt2], bfv[ct], acc1[rt2][ct], 0, 0, 0);
        }
        // elementwise: build A (bf16), P=I+A (f32+bf16), attn -> global
#pragma unroll
        for (int rt2 = 0; rt2 < 2; ++rt2)
#pragma unroll
            for (int ct = 0; ct < 4; ++ct)
#pragma unroll
                for (int j = 0; j < 4; ++j) {
                    int rr = wave * 32 + rt2 * 16 + (lane >> 4) * 4 + j;
                    int cc = ct * 16 + (lane & 15);
                    float val = acc1[rt2][ct][j];
                    if (rr < 64) {
                        float av = (rr > cc) ? -be_s[rr] * expf(gc_s[rr] - gc_s[cc]) * val : 0.f;
                        unsigned short ab = f2bf(av);
                        Ab[rr * 104 + cc] = ab;
                        Atb[cc * 104 + rr] = ab;
                        float pv = (rr == cc) ? 1.f : av;
                        Pf[rr * 68 + cc] = pv;
                        unsigned short pb = f2bf(pv);
                        Pb[rr * 104 + cc] = pb;
                        Ptb[cc * 104 + rr] = pb;
                    } else {
                        int ar = rr - 64;
                        float av = (ar >= cc) ? expf(gc_s[ar] - gc_s[cc]) * val : 0.f;
                        at_ws[base * (64 * 64) + ar * 64 + cc] = av;
                    }
                }
    }
    __syncthreads();

    // ---- doubling: T = (I+A)(I+A^2)(I+A^4)(I+A^8)(I+A^16)(I+A^32) ----
#pragma unroll 1
    for (int lev = 0; lev < 5; ++lev) {
        // D = Apow @ Apow
        f32x4 d[4] = {};
#pragma unroll
        for (int ks = 0; ks < 2; ++ks) {
            int ko = ks * 32 + (lane >> 4) * 8;
            short8 a0 = *(const short8*)&Ab[(wave * 16 + (lane & 15)) * 104 + ko];
#pragma unroll
            for (int ct = 0; ct < 4; ++ct) {
                short8 b0 = *(const short8*)&Atb[(ct * 16 + (lane & 15)) * 104 + ko];
                d[ct] = __builtin_amdgcn_mfma_f32_16x16x32_bf16(a0, b0, d[ct], 0, 0, 0);
            }
        }
        __syncthreads();
#pragma unroll
        for (int ct = 0; ct < 4; ++ct)
#pragma unroll
            for (int j = 0; j < 4; ++j) {
                int rr = wave * 16 + (lane >> 4) * 4 + j;
                int cc = ct * 16 + (lane & 15);
                unsigned short hb = f2bf(d[ct][j]);
                Ab[rr * 104 + cc] = hb;
                Atb[cc * 104 + rr] = hb;
            }
        __syncthreads();
        // P = P + Apow_new @ P
        f32x4 e[4];
#pragma unroll
        for (int ct = 0; ct < 4; ++ct)
#pragma unroll
            for (int j = 0; j < 4; ++j)
                e[ct][j] = Pf[(wave * 16 + (lane >> 4) * 4 + j) * 68 + ct * 16 + (lane & 15)];
#pragma unroll
        for (int ks = 0; ks < 2; ++ks) {
            int ko = ks * 32 + (lane >> 4) * 8;
            short8 a0 = *(const short8*)&Ab[(wave * 16 + (lane & 15)) * 104 + ko];
#pragma unroll
            for (int ct = 0; ct < 4; ++ct) {
                short8 b0 = *(const short8*)&Ptb[(ct * 16 + (lane & 15)) * 104 + ko];
                e[ct] = __builtin_amdgcn_mfma_f32_16x16x32_bf16(a0, b0, e[ct], 0, 0, 0);
            }
        }
        __syncthreads();
#pragma unroll
        for (int ct = 0; ct < 4; ++ct)
#pragma unroll
            for (int j = 0; j < 4; ++j) {
                int rr = wave * 16 + (lane >> 4) * 4 + j;
                int cc = ct * 16 + (lane & 15);
                float pv = e[ct][j];
                Pf[rr * 68 + cc] = pv;
                unsigned short pb = f2bf(pv);
                Pb[rr * 104 + cc] = pb;
                Ptb[cc * 104 + rr] = pb;
            }
        __syncthreads();
    }

    // ---- u/w = T @ [v*beta | k*beta*e^gc] ----
#pragma unroll 1
    for (int i = 0; i < 18; ++i) {
        int id = wave * 18 + i;
        int rt = id & 3, ct = id >> 2; // rt 0..3, ct 0..17
        f32x4 o4 = {};
#pragma unroll
        for (int ks = 0; ks < 2; ++ks) {
            int ko = ks * 32 + (lane >> 4) * 8;
            short8 a0 = *(const short8*)&Pb[(rt * 16 + (lane & 15)) * 104 + ko];
            short8 b0 = (ct < 12)
                ? *(const short8*)&RHSv[(ct * 16 + (lane & 15)) * 72 + ko]
                : *(const short8*)&RHSw[((ct - 12) * 16 + (lane & 15)) * 72 + ko];
            o4 = __builtin_amdgcn_mfma_f32_16x16x32_bf16(a0, b0, o4, 0, 0, 0);
        }
#pragma unroll
        for (int j = 0; j < 4; ++j) {
            int rr = rt * 16 + (lane >> 4) * 4 + j;
            int nn = ct * 16 + (lane & 15);
            if (ct < 12) u_ws[base * (64 * 192) + rr * 192 + nn] = o4[j];
            else         w_ws[base * (64 * 96) + rr * 96 + (nn - 192)] = o4[j];
        }
    }
    if (tid == 0) gl_ws[base] = gl;
}

// ---------------- phase 2a: sequential recurrence only ----------------
__global__ __launch_bounds__(256) void phase2a(const float* __restrict__ u_ws, const float* __restrict__ w_ws,
                                               const float* __restrict__ kd_ws, const float* __restrict__ gl_ws,
                                               float* __restrict__ vn_ws, float* __restrict__ s_ws) {
    int sl = blockIdx.x, h = blockIdx.y;
    int c0 = sl * 16;
    int tid = threadIdx.x;
    __shared__ float w_s[64][100];
    __shared__ float kd_s[64][100];
    __shared__ float S_s[96][20];
    __shared__ float vn_s[64][20];
    int r1 = tid >> 2, dg = tid & 3;
    int d2 = tid % 96, cq = tid / 96;
    bool act2 = tid < 192;
    float Sreg[8];
#pragma unroll
    for (int j = 0; j < 8; ++j) Sreg[j] = 0.f;
    for (int idx = tid; idx < 96 * 20; idx += 256) (&S_s[0][0])[idx] = 0.f;
    __syncthreads();
    for (int n = 0; n < NCHUNK; ++n) {
        size_t base = (size_t)(h * NCHUNK + n);
        const float* wp = w_ws + base * (64 * 96);
        const float* kdp = kd_ws + base * (64 * 96);
        const float* up = u_ws + base * (64 * 192);
        float* vnp = vn_ws + base * (64 * 192);
        float* sp = s_ws + base * (96 * 192);
        float egl = expf(gl_ws[base]);
        float4 wst[6], kst[6];
#pragma unroll
        for (int j = 0; j < 6; ++j) {
            int f = j * 256 + tid;
            wst[j] = ((const float4*)wp)[f];
            kst[j] = ((const float4*)kdp)[f];
        }
        float4 u4 = *(const float4*)(up + (size_t)r1 * 192 + c0 + dg * 4);
        if (act2) {
            *(float4*)(sp + (size_t)d2 * 192 + c0 + cq * 8)     = *(float4*)&Sreg[0];
            *(float4*)(sp + (size_t)d2 * 192 + c0 + cq * 8 + 4) = *(float4*)&Sreg[4];
        }
#pragma unroll
        for (int j = 0; j < 6; ++j) {
            int f = j * 256 + tid;
            int rr = f / 24, cc4 = (f % 24) * 4;
            *(float4*)&w_s[rr][cc4] = wst[j];
            *(float4*)&kd_s[rr][cc4] = kst[j];
        }
        __syncthreads();
        float acc[16];
#pragma unroll
        for (int c = 0; c < 16; ++c) acc[c] = 0.f;
        for (int i = 0; i < 24; ++i) {
            int d = i * 4 + dg;
            float wv = w_s[r1][d];
            float4 s0 = *(const float4*)&S_s[d][0];
            float4 s1 = *(const float4*)&S_s[d][4];
            float4 s2 = *(const float4*)&S_s[d][8];
            float4 s3 = *(const float4*)&S_s[d][12];
            acc[0] += wv * s0.x; acc[1] += wv * s0.y; acc[2] += wv * s0.z; acc[3] += wv * s0.w;
            acc[4] += wv * s1.x; acc[5] += wv * s1.y; acc[6] += wv * s1.z; acc[7] += wv * s1.w;
            acc[8] += wv * s2.x; acc[9] += wv * s2.y; acc[10] += wv * s2.z; acc[11] += wv * s2.w;
            acc[12] += wv * s3.x; acc[13] += wv * s3.y; acc[14] += wv * s3.z; acc[15] += wv * s3.w;
        }
        bool hi2 = (dg & 2) != 0, hi1 = (dg & 1) != 0;
        float half8[8], fin[4];
#pragma unroll
        for (int j = 0; j < 8; ++j) {
            float mine = hi2 ? acc[8 + j] : acc[j];
            float yours = hi2 ? acc[j] : acc[8 + j];
            half8[j] = mine + __shfl_xor(yours, 2, 64);
        }
#pragma unroll
        for (int j = 0; j < 4; ++j) {
            float mine = hi1 ? half8[4 + j] : half8[j];
            float yours = hi1 ? half8[j] : half8[4 + j];
            fin[j] = mine + __shfl_xor(yours, 1, 64);
        }
        float4 vn4;
        vn4.x = u4.x - fin[0]; vn4.y = u4.y - fin[1]; vn4.z = u4.z - fin[2]; vn4.w = u4.w - fin[3];
        *(float4*)&vn_s[r1][dg * 4] = vn4;
        *(float4*)(vnp + (size_t)r1 * 192 + c0 + dg * 4) = vn4;
        __syncthreads();
        if (act2) {
            float a2[8];
#pragma unroll
            for (int j = 0; j < 8; ++j) a2[j] = 0.f;
            for (int rr = 0; rr < 64; ++rr) {
                float kv = kd_s[rr][d2];
                float4 v0 = *(const float4*)&vn_s[rr][cq * 8];
                float4 v1 = *(const float4*)&vn_s[rr][cq * 8 + 4];
                a2[0] += kv * v0.x; a2[1] += kv * v0.y; a2[2] += kv * v0.z; a2[3] += kv * v0.w;
                a2[4] += kv * v1.x; a2[5] += kv * v1.y; a2[6] += kv * v1.z; a2[7] += kv * v1.w;
            }
#pragma unroll
            for (int j = 0; j < 8; ++j) Sreg[j] = egl * Sreg[j] + a2[j];
            *(float4*)&S_s[d2][cq * 8] = *(float4*)&Sreg[0];
            *(float4*)&S_s[d2][cq * 8 + 4] = *(float4*)&Sreg[4];
        }
        __syncthreads();
    }
}

// ---------------- phase 2b: parallel o = qg@S_n + at@vn ----------------
__global__ __launch_bounds__(384) void phase2b(const float* __restrict__ qg_ws, const float* __restrict__ at_ws,
                                               const float* __restrict__ s_ws, const float* __restrict__ vn_ws,
                                               float* __restrict__ o_ws) {
    int n = blockIdx.x;
    int h = blockIdx.y >> 1, ch = blockIdx.y & 1;
    int tid = threadIdx.x;
    int rg = tid / 24, cg = tid % 24;
    __shared__ float qg_s[64][100];
    __shared__ float at_s[64][68];
    size_t base = (size_t)(h * NCHUNK + n);
    const float* qgp = qg_ws + base * (64 * 96);
    const float* ap  = at_ws + base * (64 * 64);
    const float* sp  = s_ws + base * (96 * 192) + ch * 96;
    const float* vnp = vn_ws + base * (64 * 192) + ch * 96;
    for (int f = tid; f < 1536; f += 384) {
        int rr = f / 24, cc = (f % 24) * 4;
        *(float4*)&qg_s[rr][cc] = ((const float4*)qgp)[f];
    }
    for (int f = tid; f < 1024; f += 384) {
        int rr = f / 16, cc = (f % 16) * 4;
        *(float4*)&at_s[rr][cc] = ((const float4*)ap)[f];
    }
    __syncthreads();
    float acc00=0,acc01=0,acc02=0,acc03=0, acc10=0,acc11=0,acc12=0,acc13=0;
    float acc20=0,acc21=0,acc22=0,acc23=0, acc30=0,acc31=0,acc32=0,acc33=0;
    int r0 = rg * 4, cc0 = cg * 4;
#pragma unroll 4
    for (int k = 0; k < 96; ++k) {
        float4 b = *(const float4*)(sp + (size_t)k * 192 + cc0);
        float a0 = qg_s[r0][k], a1 = qg_s[r0 + 1][k], a2 = qg_s[r0 + 2][k], a3 = qg_s[r0 + 3][k];
        acc00 += a0 * b.x; acc01 += a0 * b.y; acc02 += a0 * b.z; acc03 += a0 * b.w;
        acc10 += a1 * b.x; acc11 += a1 * b.y; acc12 += a1 * b.z; acc13 += a1 * b.w;
        acc20 += a2 * b.x; acc21 += a2 * b.y; acc22 += a2 * b.z; acc23 += a2 * b.w;
        acc30 += a3 * b.x; acc31 += a3 * b.y; acc32 += a3 * b.z; acc33 += a3 * b.w;
    }
#pragma unroll 4
    for (int j = 0; j < 64; ++j) {
        float4 b = *(const float4*)(vnp + (size_t)j * 192 + cc0);
        float a0 = at_s[r0][j], a1 = at_s[r0 + 1][j], a2 = at_s[r0 + 2][j], a3 = at_s[r0 + 3][j];
        acc00 += a0 * b.x; acc01 += a0 * b.y; acc02 += a0 * b.z; acc03 += a0 * b.w;
        acc10 += a1 * b.x; acc11 += a1 * b.y; acc12 += a1 * b.z; acc13 += a1 * b.w;
        acc20 += a2 * b.x; acc21 += a2 * b.y; acc22 += a2 * b.z; acc23 += a2 * b.w;
        acc30 += a3 * b.x; acc31 += a3 * b.y; acc32 += a3 * b.z; acc33 += a3 * b.w;
    }
    int t0 = n * CHUNKN;
    size_t ob = (size_t)(t0 + r0) * VDIMN + h * DVN + ch * 96 + cc0;
    *(float4*)(o_ws + ob)             = make_float4(acc00, acc01, acc02, acc03);
    *(float4*)(o_ws + ob + VDIMN)     = make_float4(acc10, acc11, acc12, acc13);
    *(float4*)(o_ws + ob + 2 * VDIMN) = make_float4(acc20, acc21, acc22, acc23);
    *(float4*)(o_ws + ob + 3 * VDIMN) = make_float4(acc30, acc31, acc32, acc33);
}

// ---------------- gate (SiLU) + RMSNorm -> bf16 ----------------
__global__ __launch_bounds__(64) void gate_norm(const float* __restrict__ o_ws, const float* __restrict__ Cgate,
                                                const float* __restrict__ nw, unsigned short* __restrict__ obf) {
    int b = blockIdx.x;
    int t = b >> 4, h = b & 15;
    int lane = threadIdx.x;
    float x[3];
    float ss = 0.f;
    size_t ob = (size_t)t * VDIMN + h * DVN;
    for (int j = 0; j < 3; ++j) {
        int d = j * 64 + lane;
        float ov = o_ws[ob + d];
        float gv = Cgate[ob + d];
        float xv = ov * siluf(gv);
        x[j] = xv;
        ss += xv * xv;
    }
    for (int off = 32; off > 0; off >>= 1) ss += __shfl_xor(ss, off, 64);
    float r = rsqrtf(ss * (1.f / 192.f) + EPSF);
    for (int j = 0; j < 3; ++j) {
        int d = j * 64 + lane;
        obf[ob + d] = f2bf(x[j] * r * nw[d]);
    }
}

extern "C" void kernel_launch(void* const* d_in, const int* in_sizes, int n_in,
                              void* d_out, int out_size, void* d_ws, size_t ws_size,
                              hipStream_t stream) {
    (void)in_sizes; (void)n_in; (void)out_size;
    const float* X    = (const float*)d_in[0];
    const float* Wq   = (const float*)d_in[1];
    const float* Wk   = (const float*)d_in[2];
    const float* Wv   = (const float*)d_in[3];
    const float* Wb   = (const float*)d_in[4];
    const float* Wa   = (const float*)d_in[5];
    const float* Wg   = (const float*)d_in[6];
    const float* Wo   = (const float*)d_in[7];
    const float* cq   = (const float*)d_in[8];
    const float* ck   = (const float*)d_in[9];
    const float* cv   = (const float*)d_in[10];
    const float* Alog = (const float*)d_in[11];
    const float* dtb  = (const float*)d_in[12];
    const float* nw   = (const float*)d_in[13];

    const size_t OFF_XBF   = 0;
    const size_t OFF_WALLT = 8388608;
    const size_t OFF_WOT   = 46137344;
    const size_t OFF_CQKV  = 58720256;
    const size_t OFF_CGATE = 109051904;
    const size_t OFF_QPOST = 134217728;
    const size_t OFF_KPOST = 146800640;
    const size_t OFF_VPOST = 159383552;
    const size_t OFF_GVEC  = 184549376;
    const size_t OFF_BVEC  = 184680448;
    const size_t OFF_GL    = 184811520;
    const size_t OFF_U     = 184819712;
    const size_t OFF_W     = 209985536;
    const size_t OFF_QG    = 222568448;
    const size_t OFF_KD    = 235151360;
    const size_t OFF_AT    = OFF_XBF;
    const size_t OFF_S     = OFF_CQKV;
    const size_t OFF_O     = OFF_QPOST;
    const size_t OFF_OBF   = OFF_VPOST;
    const size_t NEEDED    = 247734272;
    if (ws_size < NEEDED) return;

    char* ws = (char*)d_ws;
    unsigned short* Xbf   = (unsigned short*)(ws + OFF_XBF);
    unsigned short* WallT = (unsigned short*)(ws + OFF_WALLT);
    unsigned short* WoT   = (unsigned short*)(ws + OFF_WOT);
    float* Cqkv  = (float*)(ws + OFF_CQKV);
    float* Cgate = (float*)(ws + OFF_CGATE);
    float* qpost = (float*)(ws + OFF_QPOST);
    float* kpost = (float*)(ws + OFF_KPOST);
    float* vpost = (float*)(ws + OFF_VPOST);
    float* gvec  = (float*)(ws + OFF_GVEC);
    float* bvec  = (float*)(ws + OFF_BVEC);
    float* gl_ws = (float*)(ws + OFF_GL);
    float* u_ws  = (float*)(ws + OFF_U);
    float* w_ws  = (float*)(ws + OFF_W);
    float* qg_ws = (float*)(ws + OFF_QG);
    float* kd_ws = (float*)(ws + OFF_KD);
    float* at_ws = (float*)(ws + OFF_AT);
    float* s_ws  = (float*)(ws + OFF_S);
    float* o_ws  = (float*)(ws + OFF_O);
    unsigned short* obf = (unsigned short*)(ws + OFF_OBF);

    cast_f32_bf16<<<4096, 256, 0, stream>>>(X, Xbf, 2048 * 2048);
    dim3 tb(64, 4);
    transpose_cast<<<dim3(1536 / 64, 2048 / 64), tb, 0, stream>>>(Wq, WallT, 2048, 1536);
    transpose_cast<<<dim3(1536 / 64, 2048 / 64), tb, 0, stream>>>(Wk, WallT + (size_t)1536 * 2048, 2048, 1536);
    transpose_cast<<<dim3(3072 / 64, 2048 / 64), tb, 0, stream>>>(Wv, WallT + (size_t)3072 * 2048, 2048, 3072);
    transpose_cast<<<dim3(3072 / 64, 2048 / 64), tb, 0, stream>>>(Wg, WallT + (size_t)6144 * 2048, 2048, 3072);
    transpose_cast<<<dim3(2048 / 64, 3072 / 64), tb, 0, stream>>>(Wo, WoT, 3072, 2048);

    gemm_bt<<<dim3(QKVD / 128, 2048 / 128), 256, 0, stream>>>(Xbf, WallT, Cqkv, 2048, QKVD, 2048);
    gemm_bt<<<dim3(VDIMN / 128, 2048 / 128), 256, 0, stream>>>(Xbf, WallT + (size_t)QKVD * 2048, Cgate, 2048, VDIMN, 2048);

    conv_silu<<<dim3(6, T_LEN), 256, 0, stream>>>(Cqkv + 0, QKVD, cq, qpost, KDIMN);
    conv_silu<<<dim3(6, T_LEN), 256, 0, stream>>>(Cqkv + 1536, QKVD, ck, kpost, KDIMN);
    conv_silu<<<dim3(12, T_LEN), 256, 0, stream>>>(Cqkv + 3072, QKVD, cv, vpost, VDIMN);
    beta_g<<<T_LEN, 256, 0, stream>>>(X, Wb, Wa, Alog, dtb, bvec, gvec);

    phase1_mfma<<<dim3(NCHUNK, HVN), 256, 0, stream>>>(qpost, kpost, vpost, gvec, bvec,
                                                       u_ws, w_ws, qg_ws, kd_ws, at_ws, gl_ws);
    phase2a<<<dim3(12, HVN), 256, 0, stream>>>(u_ws, w_ws, kd_ws, gl_ws, u_ws, s_ws);
    phase2b<<<dim3(NCHUNK, HVN * 2), 384, 0, stream>>>(qg_ws, at_ws, s_ws, u_ws, o_ws);

    gate_norm<<<T_LEN * HVN, 64, 0, stream>>>(o_ws, Cgate, nw, obf);

    gemm_bt<<<dim3(2048 / 128, 2048 / 128), 256, 0, stream>>>(obf, WoT, (float*)d_out, 2048, 2048, 3072);
}